// Round 6
// baseline (3564.417 us; speedup 1.0000x reference)
//
#include <hip/hip_runtime.h>

// B*H*W = 65536 vectors, dim 64, 512 codes
#define NVEC 65536
#define DIM 64
#define KCODES 512
#define NBLK 1024  // NVEC / 64

// Pre-kernel: codebook norms once for the whole GPU (was per-block before).
__global__ __launch_bounds__(512, 1) void norms_kernel(const float* __restrict__ emb,
                                                       float* __restrict__ en_out) {
    const int k = threadIdx.x;  // 512 threads, one code each, coalesced over k
    float s = 0.f;
#pragma unroll
    for (int d = 0; d < DIM; ++d) {
        float v = emb[d * KCODES + k];
        s = fmaf(v, v, s);
    }
    en_out[k] = s;
}

// Main: 256 threads = 4 waves on the SAME 64 vectors (one per lane).
// z lives in LDS transposed ([dq][vec] float4 -> per-lane reads are fully
// contiguous, conflict-free) -- no per-lane residency fight, no scalar pipe.
// Each wave scans a wave-uniform 128-code slice; emb staged per-wave in a
// single 4KB 16-code tile (reg-staged prefetch, own-buffer => no barriers in
// the main loop); inner loop reads emb via uniform-address LDS broadcasts.
// Grid: 1024 blocks, LDS 36.3KB -> 4 blocks/CU = 16 waves/CU.
__global__ __launch_bounds__(256, 4) void vq_kernel(const float* __restrict__ x,
                                                    const float* __restrict__ emb,
                                                    const float* __restrict__ en_g,
                                                    float* __restrict__ out,
                                                    float* __restrict__ ws) {
    __shared__ float4 zb[16 * 64];     // [dq][vec] : 16KB, z transposed
    __shared__ float4 ebuf[4][256];    // per-wave 16-code tile [d*4+j4] : 16KB
    __shared__ float  en[KCODES];      // 2KB
    __shared__ float  sdist[4][64];
    __shared__ int    sidx[4][64];
    __shared__ float  swl[4];

    const int tid  = threadIdx.x;
    const int wid  = __builtin_amdgcn_readfirstlane(tid >> 6);  // 0..3 (SGPR)
    const int lane = tid & 63;

    // norms from pre-kernel (2 coalesced dwords/thread)
    en[tid]       = en_g[tid];
    en[tid + 256] = en_g[tid + 256];

    // cooperative transposed z load: 4 coalesced float4 per thread
    const float4* x4 = reinterpret_cast<const float4*>(x + (size_t)blockIdx.x * 64 * DIM);
#pragma unroll
    for (int i = 0; i < 4; ++i) {
        const int f = i * 256 + tid;            // float4 index in 64x64 chunk
        zb[(f & 15) * 64 + (f >> 4)] = x4[f];   // [dq = f&15][vec = f>>4]
    }
    __syncthreads();

    // ||z||^2 for this lane's vector (16 contiguous b128 reads)
    float znorm = 0.f;
#pragma unroll
    for (int dq = 0; dq < 16; ++dq) {
        float4 v = zb[dq * 64 + lane];
        znorm = fmaf(v.x, v.x, znorm);
        znorm = fmaf(v.y, v.y, znorm);
        znorm = fmaf(v.z, v.z, znorm);
        znorm = fmaf(v.w, v.w, znorm);
    }

    // staging geometry: lane stages 4 float4 of the 16-code x 64-d tile
    const int r0 = lane >> 2;         // d-row within 16-row group
    const int c4 = lane & 3;          // float4-column (4 codes)
    const int kbase0 = wid * 128;     // this wave's code slice (wave-uniform)
    const float4* emb4 = reinterpret_cast<const float4*>(emb);

    // prologue: stage tile 0 into this wave's buffer
    {
        float4 st[4];
#pragma unroll
        for (int i = 0; i < 4; ++i)
            st[i] = emb4[(i * 16 + r0) * (KCODES / 4) + (kbase0 >> 2) + c4];
#pragma unroll
        for (int i = 0; i < 4; ++i) ebuf[wid][i * 64 + lane] = st[i];
    }

    float best  = 3.4e38f;
    int   bestk = 0;

#pragma unroll 1
    for (int t = 0; t < 8; ++t) {
        const int kb = kbase0 + t * 16;

        // issue next tile's global loads early (hidden under the d-loop)
        float4 stn[4];
        if (t < 7) {
#pragma unroll
            for (int i = 0; i < 4; ++i)
                stn[i] = emb4[(i * 16 + r0) * (KCODES / 4) + ((kb + 16) >> 2) + c4];
        }

        float acc[16];
#pragma unroll
        for (int j = 0; j < 16; ++j) acc[j] = 0.f;

        const float4* eb = ebuf[wid];
#pragma unroll
        for (int dq = 0; dq < 16; ++dq) {
            const float4 zq = zb[dq * 64 + lane];   // contiguous, conflict-free
#pragma unroll
            for (int dd = 0; dd < 4; ++dd) {
                const int d = dq * 4 + dd;
                const float zd = (dd == 0) ? zq.x : (dd == 1) ? zq.y : (dd == 2) ? zq.z : zq.w;
#pragma unroll
                for (int j4 = 0; j4 < 4; ++j4) {
                    const float4 e4 = eb[d * 4 + j4];  // uniform addr -> LDS broadcast
                    acc[j4 * 4 + 0] = fmaf(zd, e4.x, acc[j4 * 4 + 0]);
                    acc[j4 * 4 + 1] = fmaf(zd, e4.y, acc[j4 * 4 + 1]);
                    acc[j4 * 4 + 2] = fmaf(zd, e4.z, acc[j4 * 4 + 2]);
                    acc[j4 * 4 + 3] = fmaf(zd, e4.w, acc[j4 * 4 + 3]);
                }
            }
        }

        // write next tile (own buffer; wave has finished reading tile t)
        if (t < 7) {
#pragma unroll
            for (int i = 0; i < 4; ++i) ebuf[wid][i * 64 + lane] = stn[i];
        }

        // distances: reference association (||z||^2 + ||e||^2) - 2*dot
#pragma unroll
        for (int j = 0; j < 16; ++j) {
            float tt   = znorm + en[kb + j];
            float dist = fmaf(-2.0f, acc[j], tt);
            if (dist < best) { best = dist; bestk = kb + j; }  // ascending k, first min
        }
    }

    sdist[wid][lane] = best;
    sidx[wid][lane]  = bestk;
    __syncthreads();

    // --- epilogue: thread t -> vector v16 = t>>2, dim-block j16 = (t&3)*16 ---
    const int v16 = tid >> 2;
    const int j16 = (tid & 3) * 16;
    float bd = sdist[0][v16];
    int   bk = sidx[0][v16];
#pragma unroll
    for (int s = 1; s < 4; ++s) {   // ascending-k slices; strict < keeps lowest k
        float d2 = sdist[s][v16];
        int   k2 = sidx[s][v16];
        if (d2 < bd) { bd = d2; bk = k2; }
    }

    const int gvec = blockIdx.x * 64 + v16;
    float* og = out + (size_t)gvec * DIM + j16;

    float lossLocal = 0.f;
#pragma unroll
    for (int c = 0; c < 4; ++c) {
        float4 q;
        q.x = emb[(j16 + c * 4 + 0) * KCODES + bk];
        q.y = emb[(j16 + c * 4 + 1) * KCODES + bk];
        q.z = emb[(j16 + c * 4 + 2) * KCODES + bk];
        q.w = emb[(j16 + c * 4 + 3) * KCODES + bk];
        *reinterpret_cast<float4*>(og + c * 4) = q;  // contiguous 4KB per wave
        const float4 xa = zb[((tid & 3) * 4 + c) * 64 + v16];  // x from LDS
        float a;
        a = q.x - xa.x; lossLocal = fmaf(a, a, lossLocal);
        a = q.y - xa.y; lossLocal = fmaf(a, a, lossLocal);
        a = q.z - xa.z; lossLocal = fmaf(a, a, lossLocal);
        a = q.w - xa.w; lossLocal = fmaf(a, a, lossLocal);
    }

    // --- block-reduce loss, atomic accumulate, last block finalizes ---
#pragma unroll
    for (int off = 32; off; off >>= 1) lossLocal += __shfl_down(lossLocal, off, 64);
    if (lane == 0) swl[wid] = lossLocal;
    __syncthreads();
    if (tid == 0) {
        float s = swl[0] + swl[1] + swl[2] + swl[3];
        atomicAdd(&ws[0], s);
        __threadfence();
        unsigned int* cnt = reinterpret_cast<unsigned int*>(ws + 1);
        unsigned int prev = atomicAdd(cnt, 1u);
        if (prev == (unsigned int)(NBLK - 1)) {
            float total = atomicAdd(&ws[0], 0.0f);  // coherent read of final sum
            out[(size_t)NVEC * DIM] = 2.0f * total / (float)((size_t)NVEC * DIM);
        }
    }
}

extern "C" void kernel_launch(void* const* d_in, const int* in_sizes, int n_in,
                              void* d_out, int out_size, void* d_ws, size_t ws_size,
                              hipStream_t stream) {
    const float* x   = (const float*)d_in[0];
    const float* emb = (const float*)d_in[1];
    float* out = (float*)d_out;
    float* ws  = (float*)d_ws;
    float* en  = ws + 4;  // ws[0]=loss, ws[1]=counter, en at ws[4..516)

    hipMemsetAsync(d_ws, 0, 8, stream);  // loss accumulator + block counter
    norms_kernel<<<dim3(1), dim3(512), 0, stream>>>(emb, en);
    vq_kernel<<<dim3(NBLK), dim3(256), 0, stream>>>(x, emb, en, out, ws);
}

// Round 7
// 94.628 us; speedup vs baseline: 37.6677x; 37.6677x over previous
//
#include <hip/hip_runtime.h>

// B*H*W = 65536 vectors, dim 64, 512 codes
#define NVEC 65536
#define DIM 64
#define KCODES 512
#define NBLK 1024   // NVEC / 64
#define NTILE 32    // 512 codes / 16 per MFMA col-tile
#define ELS 2048.0f // residual pre-scale (keeps fp16 residuals out of denormal range)

typedef _Float16 f16x8 __attribute__((ext_vector_type(8)));
typedef float    f32x4 __attribute__((ext_vector_type(4)));
typedef unsigned long long u64;

// ws layout (floats): [0] loss, [1] counter, [4..516) en,
// [1024..17408) eh frags (4096 f16x8), [17408..33792) el frags.
#define WS_EN 4
#define WS_EH 1024
#define WS_EL (1024 + 16384)

// Prep: exact codebook norms (reference-association fmaf chain) + pack E into
// per-lane MFMA B-fragments (hi fp16 and scaled-residual fp16), so the main
// loop's B-operand is ONE coalesced 16B load per fragment.
__global__ __launch_bounds__(512, 1) void prep_kernel(const float* __restrict__ emb,
                                                      float* __restrict__ ws) {
    const int tid = threadIdx.x;
    if (blockIdx.x == 0) {
        float s = 0.f;
#pragma unroll
        for (int d = 0; d < DIM; ++d) { float v = emb[d * KCODES + tid]; s = fmaf(v, v, s); }
        ws[WS_EN + tid] = s;
    } else {
        const int fl = (blockIdx.x - 1) * 512 + tid;   // fragment-lane id, 0..4095
        const int ct = fl >> 7, s5 = (fl >> 6) & 1, l = fl & 63;
        const int k  = ct * 16 + (l & 15);             // B col
        const int d0 = s5 * 32 + (l >> 4) * 8;         // B k-rows (d)
        f16x8 eh, el;
#pragma unroll
        for (int e = 0; e < 8; ++e) {
            float v = emb[(d0 + e) * KCODES + k];
            _Float16 h = (_Float16)v;
            eh[e] = h;
            el[e] = (_Float16)((v - (float)h) * ELS);
        }
        ((f16x8*)(ws + WS_EH))[fl] = eh;
        ((f16x8*)(ws + WS_EL))[fl] = el;
    }
}

// Main: block = 256 thr = 4 waves; each wave owns 16 vectors (A-tile) and
// scans all 512 codes in 32 MFMA col-tiles (6 mfma_f32_16x16x32_f16 each:
// zh*eh + (zl_s*eh + zh*el_s)/2048). Per-lane packed-u64 top-2, 16-lane
// shfl reduce, exact fp32 rescore of both candidates (bit-identical chain
// to rounds 1-6), then the proven gather/loss epilogue.
__global__ __launch_bounds__(256, 2) void vq_kernel(const float* __restrict__ x,
                                                    const float* __restrict__ emb,
                                                    const float* __restrict__ ws_ro,
                                                    float* __restrict__ out,
                                                    float* __restrict__ ws) {
    __shared__ f16x8 zhS[64][8];   // [v][u] u = (d>>3) ^ (v&7)  (bank swizzle)
    __shared__ f16x8 zlS[64][8];
    __shared__ float enS[KCODES];
    __shared__ float znS[64];
    __shared__ int   cand[64][2];
    __shared__ float exd[64][2];
    __shared__ int   bksel[64];
    __shared__ float swl[4];

    const int tid  = threadIdx.x;
    const int wid  = tid >> 6;
    const int lane = tid & 63;
    const size_t xbase = (size_t)blockIdx.x * 64 * DIM;

    enS[tid]       = ws_ro[WS_EN + tid];
    enS[tid + 256] = ws_ro[WS_EN + tid + 256];

    // convert x-block to fp16 hi + scaled residual, swizzled stores
    {
        const int v  = tid >> 2;
        const int d0 = (tid & 3) * 16;
        const float* xp = x + xbase + v * DIM + d0;
        float4 a = *(const float4*)(xp);
        float4 b = *(const float4*)(xp + 4);
        float4 c = *(const float4*)(xp + 8);
        float4 e = *(const float4*)(xp + 12);
        float t0[8] = {a.x, a.y, a.z, a.w, b.x, b.y, b.z, b.w};
        float t1[8] = {c.x, c.y, c.z, c.w, e.x, e.y, e.z, e.w};
        f16x8 h0, l0, h1, l1;
#pragma unroll
        for (int i = 0; i < 8; ++i) {
            _Float16 h = (_Float16)t0[i]; h0[i] = h; l0[i] = (_Float16)((t0[i] - (float)h) * ELS);
            _Float16 g = (_Float16)t1[i]; h1[i] = g; l1[i] = (_Float16)((t1[i] - (float)g) * ELS);
        }
        const int u0 = ((d0 >> 3))     ^ (v & 7);
        const int u1 = ((d0 >> 3) + 1) ^ (v & 7);
        zhS[v][u0] = h0; zhS[v][u1] = h1;
        zlS[v][u0] = l0; zlS[v][u1] = l1;
    }
    // exact ||z||^2 (ascending-d fmaf chain, same as rounds 1-6)
    if (tid < 64) {
        const float* xr = x + xbase + tid * DIM;
        float s = 0.f;
#pragma unroll
        for (int d = 0; d < DIM; ++d) s = fmaf(xr[d], xr[d], s);
        znS[tid] = s;
    }
    __syncthreads();

    // A-fragments: row = lane&15 (vector), k = (lane>>4)*8 + e  (+32 for s=1)
    const int vb = wid * 16;
    const int vA = vb + (lane & 15);
    const int g4 = lane >> 4;
    const int sw = vA & 7;
    f16x8 ah0 = zhS[vA][(g4)     ^ sw];
    f16x8 ah1 = zhS[vA][(4 + g4) ^ sw];
    f16x8 al0 = zlS[vA][(g4)     ^ sw];
    f16x8 al1 = zlS[vA][(4 + g4) ^ sw];
    const float zn0 = znS[vb + g4 * 4 + 0];
    const float zn1 = znS[vb + g4 * 4 + 1];
    const float zn2 = znS[vb + g4 * 4 + 2];
    const float zn3 = znS[vb + g4 * 4 + 3];

    const f16x8* ehp = (const f16x8*)(ws_ro + WS_EH);
    const f16x8* elp = (const f16x8*)(ws_ro + WS_EL);

    u64 p1_0 = ~0ull, p1_1 = ~0ull, p1_2 = ~0ull, p1_3 = ~0ull;
    u64 p2_0 = ~0ull, p2_1 = ~0ull, p2_2 = ~0ull, p2_3 = ~0ull;

#pragma unroll 2
    for (int ct = 0; ct < NTILE; ++ct) {
        f16x8 bh0 = ehp[(ct * 2 + 0) * 64 + lane];
        f16x8 bh1 = ehp[(ct * 2 + 1) * 64 + lane];
        f16x8 bl0 = elp[(ct * 2 + 0) * 64 + lane];
        f16x8 bl1 = elp[(ct * 2 + 1) * 64 + lane];
        f32x4 acch = {0.f, 0.f, 0.f, 0.f};
        f32x4 accm = {0.f, 0.f, 0.f, 0.f};
        acch = __builtin_amdgcn_mfma_f32_16x16x32_f16(ah0, bh0, acch, 0, 0, 0);
        acch = __builtin_amdgcn_mfma_f32_16x16x32_f16(ah1, bh1, acch, 0, 0, 0);
        accm = __builtin_amdgcn_mfma_f32_16x16x32_f16(al0, bh0, accm, 0, 0, 0);
        accm = __builtin_amdgcn_mfma_f32_16x16x32_f16(al1, bh1, accm, 0, 0, 0);
        accm = __builtin_amdgcn_mfma_f32_16x16x32_f16(ah0, bl0, accm, 0, 0, 0);
        accm = __builtin_amdgcn_mfma_f32_16x16x32_f16(ah1, bl1, accm, 0, 0, 0);
        const int   kk  = ct * 16 + (lane & 15);   // C/D col = lane&15
        const float enk = enS[kk];
#define UPD(J, PJ1, PJ2, ZNJ) { \
        float dot  = acch[J] + accm[J] * (1.0f / ELS); \
        float dist = fmaf(-2.0f, dot, ZNJ + enk); \
        u64 p  = ((u64)__float_as_uint(dist) << 32) | (unsigned)kk; \
        u64 mx = p > PJ1 ? p : PJ1; \
        PJ1 = p < PJ1 ? p : PJ1; \
        PJ2 = mx < PJ2 ? mx : PJ2; }
        UPD(0, p1_0, p2_0, zn0) UPD(1, p1_1, p2_1, zn1)
        UPD(2, p1_2, p2_2, zn2) UPD(3, p1_3, p2_3, zn3)
#undef UPD
    }

    // top-2 merge across the 16 lanes sharing each vector row
#pragma unroll
    for (int m = 1; m <= 8; m <<= 1) {
#define RED(PJ1, PJ2) { \
        u64 q1 = __shfl_xor(PJ1, m); u64 q2 = __shfl_xor(PJ2, m); \
        u64 lo = PJ1 < q1 ? PJ1 : q1; u64 hi = PJ1 < q1 ? q1 : PJ1; \
        u64 s2 = PJ2 < q2 ? PJ2 : q2; \
        PJ1 = lo; PJ2 = hi < s2 ? hi : s2; }
        RED(p1_0, p2_0) RED(p1_1, p2_1) RED(p1_2, p2_2) RED(p1_3, p2_3)
#undef RED
    }
    {
        const int j = lane & 15;
        if (j < 4) {
            u64 s1 = j == 0 ? p1_0 : j == 1 ? p1_1 : j == 2 ? p1_2 : p1_3;
            u64 s2 = j == 0 ? p2_0 : j == 1 ? p2_1 : j == 2 ? p2_2 : p2_3;
            const int v = vb + g4 * 4 + j;
            cand[v][0] = (int)(unsigned)s1;
            cand[v][1] = (int)(unsigned)s2;
        }
    }
    __syncthreads();

    // exact fp32 rescore of both candidates — bit-identical chain to R1-R6
    if (tid < 128) {
        const int v = tid >> 1, c = tid & 1;
        const int k = cand[v][c];
        const float* xr = x + xbase + v * DIM;
        float dot = 0.f;
#pragma unroll
        for (int d = 0; d < DIM; ++d) dot = fmaf(xr[d], emb[d * KCODES + k], dot);
        exd[v][c] = fmaf(-2.0f, dot, znS[v] + enS[k]);
    }
    __syncthreads();
    if (tid < 64) {
        const int k0 = cand[tid][0], k1 = cand[tid][1];
        const float d0 = exd[tid][0], d1 = exd[tid][1];
        const bool take2 = (d1 < d0) || (d1 == d0 && k1 < k0);
        bksel[tid] = take2 ? k1 : k0;
    }
    __syncthreads();

    // epilogue (R3's proven form): thread -> (vector v16, dim-block j16)
    const int v16 = tid >> 2;
    const int j16 = (tid & 3) * 16;
    const int bk  = bksel[v16];
    const int gvec = blockIdx.x * 64 + v16;
    const float* xg = x + (size_t)gvec * DIM + j16;
    float*       og = out + (size_t)gvec * DIM + j16;

    float lossLocal = 0.f;
#pragma unroll
    for (int c = 0; c < 4; ++c) {
        float4 q;
        q.x = emb[(j16 + c * 4 + 0) * KCODES + bk];
        q.y = emb[(j16 + c * 4 + 1) * KCODES + bk];
        q.z = emb[(j16 + c * 4 + 2) * KCODES + bk];
        q.w = emb[(j16 + c * 4 + 3) * KCODES + bk];
        *(float4*)(og + c * 4) = q;
        float4 xa = *(const float4*)(xg + c * 4);
        float a;
        a = q.x - xa.x; lossLocal = fmaf(a, a, lossLocal);
        a = q.y - xa.y; lossLocal = fmaf(a, a, lossLocal);
        a = q.z - xa.z; lossLocal = fmaf(a, a, lossLocal);
        a = q.w - xa.w; lossLocal = fmaf(a, a, lossLocal);
    }

#pragma unroll
    for (int off = 32; off; off >>= 1) lossLocal += __shfl_down(lossLocal, off, 64);
    if (lane == 0) swl[wid] = lossLocal;
    __syncthreads();
    if (tid == 0) {
        float s = swl[0] + swl[1] + swl[2] + swl[3];
        atomicAdd(&ws[0], s);
        __threadfence();
        unsigned int* cnt = (unsigned int*)(ws + 1);
        unsigned int prev = atomicAdd(cnt, 1u);
        if (prev == (unsigned int)(NBLK - 1)) {
            float total = atomicAdd(&ws[0], 0.0f);
            out[(size_t)NVEC * DIM] = 2.0f * total / (float)((size_t)NVEC * DIM);
        }
    }
}

extern "C" void kernel_launch(void* const* d_in, const int* in_sizes, int n_in,
                              void* d_out, int out_size, void* d_ws, size_t ws_size,
                              hipStream_t stream) {
    const float* x   = (const float*)d_in[0];
    const float* emb = (const float*)d_in[1];
    float* out = (float*)d_out;
    float* ws  = (float*)d_ws;

    hipMemsetAsync(d_ws, 0, 8, stream);  // loss accumulator + block counter
    prep_kernel<<<dim3(9), dim3(512), 0, stream>>>(emb, ws);
    vq_kernel<<<dim3(NBLK), dim3(256), 0, stream>>>(x, emb, ws, out, ws);
}

// Round 8
// 57.364 us; speedup vs baseline: 62.1374x; 1.6496x over previous
//
#include <hip/hip_runtime.h>

// B*H*W = 65536 vectors, dim 64, 512 codes
#define NVEC 65536
#define DIM 64
#define KCODES 512
#define NBLK 1024   // NVEC / 64
#define NTILE 32    // 512 codes / 16 per MFMA col-tile
#define ELS 2048.0f // residual pre-scale (keeps fp16 residuals out of denormal range)

typedef _Float16 f16x8 __attribute__((ext_vector_type(8)));
typedef float    f32x4 __attribute__((ext_vector_type(4)));
typedef unsigned long long u64;

// ws layout (floats): [4..516) en, [1024..17408) eh frags, [17408..33792) el
// frags, [33792..34816) per-block loss partials.
#define WS_EN 4
#define WS_EH 1024
#define WS_EL (1024 + 16384)
#define WS_PART 33792

// Prep: exact codebook norms + pack E into per-lane MFMA B-fragments
// (hi fp16 and scaled-residual fp16) so main-loop B loads are coalesced 16B.
__global__ __launch_bounds__(512, 1) void prep_kernel(const float* __restrict__ emb,
                                                      float* __restrict__ ws) {
    const int tid = threadIdx.x;
    if (blockIdx.x == 0) {
        float s = 0.f;
#pragma unroll
        for (int d = 0; d < DIM; ++d) { float v = emb[d * KCODES + tid]; s = fmaf(v, v, s); }
        ws[WS_EN + tid] = s;
    } else {
        const int fl = (blockIdx.x - 1) * 512 + tid;   // fragment-lane id, 0..4095
        const int ct = fl >> 7, s5 = (fl >> 6) & 1, l = fl & 63;
        const int k  = ct * 16 + (l & 15);             // B col
        const int d0 = s5 * 32 + (l >> 4) * 8;         // B k-rows (d)
        f16x8 eh, el;
#pragma unroll
        for (int e = 0; e < 8; ++e) {
            float v = emb[(d0 + e) * KCODES + k];
            _Float16 h = (_Float16)v;
            eh[e] = h;
            el[e] = (_Float16)((v - (float)h) * ELS);
        }
        ((f16x8*)(ws + WS_EH))[fl] = eh;
        ((f16x8*)(ws + WS_EL))[fl] = el;
    }
}

// Main: 256 thr = 4 waves; each wave owns 16 vectors, scans all 512 codes in
// 32 col-tiles (6 mfma_f32_16x16x32_f16: zh*eh + (zl_s*eh + zh*el_s)/2048).
// B-fragments register double-buffered (load-to-use = 1 tile). Packed-u64
// top-2 + 16-lane shfl reduce + exact fp32 rescore of both candidates.
// NO global atomics: per-block loss partial -> ws, finish kernel reduces.
__global__ __launch_bounds__(256, 4) void vq_kernel(const float* __restrict__ x,
                                                    const float* __restrict__ emb,
                                                    const float* __restrict__ ws_ro,
                                                    float* __restrict__ out,
                                                    float* __restrict__ part) {
    __shared__ f16x8 zhS[64][8];   // [v][u] u = (d>>3) ^ (v&7)  (bank swizzle)
    __shared__ f16x8 zlS[64][8];
    __shared__ float enS[KCODES];
    __shared__ float znS[64];
    __shared__ int   cand[64][2];
    __shared__ float exd[64][2];
    __shared__ int   bksel[64];
    __shared__ float swl[4];

    const int tid  = threadIdx.x;
    const int wid  = tid >> 6;
    const int lane = tid & 63;
    const size_t xbase = (size_t)blockIdx.x * 64 * DIM;

    enS[tid]       = ws_ro[WS_EN + tid];
    enS[tid + 256] = ws_ro[WS_EN + tid + 256];

    // x-block -> fp16 hi + scaled residual (swizzled LDS), znorm via shfl
    {
        const int v  = tid >> 2;
        const int d0 = (tid & 3) * 16;
        const float* xp = x + xbase + v * DIM + d0;
        float4 a = *(const float4*)(xp);
        float4 b = *(const float4*)(xp + 4);
        float4 c = *(const float4*)(xp + 8);
        float4 e = *(const float4*)(xp + 12);
        float t0[8] = {a.x, a.y, a.z, a.w, b.x, b.y, b.z, b.w};
        float t1[8] = {c.x, c.y, c.z, c.w, e.x, e.y, e.z, e.w};
        float pz = 0.f;
#pragma unroll
        for (int i = 0; i < 8; ++i) pz = fmaf(t0[i], t0[i], pz);
#pragma unroll
        for (int i = 0; i < 8; ++i) pz = fmaf(t1[i], t1[i], pz);
        pz += __shfl_xor(pz, 1);
        pz += __shfl_xor(pz, 2);   // 4-thread group shares one vector
        if ((tid & 3) == 0) znS[v] = pz;
        f16x8 h0, l0, h1, l1;
#pragma unroll
        for (int i = 0; i < 8; ++i) {
            _Float16 h = (_Float16)t0[i]; h0[i] = h; l0[i] = (_Float16)((t0[i] - (float)h) * ELS);
            _Float16 g = (_Float16)t1[i]; h1[i] = g; l1[i] = (_Float16)((t1[i] - (float)g) * ELS);
        }
        const int u0 = ((d0 >> 3))     ^ (v & 7);
        const int u1 = ((d0 >> 3) + 1) ^ (v & 7);
        zhS[v][u0] = h0; zhS[v][u1] = h1;
        zlS[v][u0] = l0; zlS[v][u1] = l1;
    }
    __syncthreads();

    // A-fragments: row = lane&15 (vector), k = (lane>>4)*8 + e  (+32 for s=1)
    const int vb = wid * 16;
    const int vA = vb + (lane & 15);
    const int g4 = lane >> 4;
    const int sw = vA & 7;
    f16x8 ah0 = zhS[vA][(g4)     ^ sw];
    f16x8 ah1 = zhS[vA][(4 + g4) ^ sw];
    f16x8 al0 = zlS[vA][(g4)     ^ sw];
    f16x8 al1 = zlS[vA][(4 + g4) ^ sw];
    const float zn0 = znS[vb + g4 * 4 + 0];
    const float zn1 = znS[vb + g4 * 4 + 1];
    const float zn2 = znS[vb + g4 * 4 + 2];
    const float zn3 = znS[vb + g4 * 4 + 3];

    const f16x8* ehp = (const f16x8*)(ws_ro + WS_EH);
    const f16x8* elp = (const f16x8*)(ws_ro + WS_EL);

    u64 p1_0 = ~0ull, p1_1 = ~0ull, p1_2 = ~0ull, p1_3 = ~0ull;
    u64 p2_0 = ~0ull, p2_1 = ~0ull, p2_2 = ~0ull, p2_3 = ~0ull;

    // register double-buffer of B-fragments
    f16x8 cbh0 = ehp[lane], cbh1 = ehp[64 + lane];
    f16x8 cbl0 = elp[lane], cbl1 = elp[64 + lane];

#pragma unroll 1
    for (int ct = 0; ct < NTILE; ++ct) {
        f16x8 nbh0, nbh1, nbl0, nbl1;
        if (ct < NTILE - 1) {
            nbh0 = ehp[(ct * 2 + 2) * 64 + lane];
            nbh1 = ehp[(ct * 2 + 3) * 64 + lane];
            nbl0 = elp[(ct * 2 + 2) * 64 + lane];
            nbl1 = elp[(ct * 2 + 3) * 64 + lane];
        }
        f32x4 acch = {0.f, 0.f, 0.f, 0.f};
        f32x4 accm = {0.f, 0.f, 0.f, 0.f};
        acch = __builtin_amdgcn_mfma_f32_16x16x32_f16(ah0, cbh0, acch, 0, 0, 0);
        acch = __builtin_amdgcn_mfma_f32_16x16x32_f16(ah1, cbh1, acch, 0, 0, 0);
        accm = __builtin_amdgcn_mfma_f32_16x16x32_f16(al0, cbh0, accm, 0, 0, 0);
        accm = __builtin_amdgcn_mfma_f32_16x16x32_f16(al1, cbh1, accm, 0, 0, 0);
        accm = __builtin_amdgcn_mfma_f32_16x16x32_f16(ah0, cbl0, accm, 0, 0, 0);
        accm = __builtin_amdgcn_mfma_f32_16x16x32_f16(ah1, cbl1, accm, 0, 0, 0);
        const int   kk  = ct * 16 + (lane & 15);   // C/D col = lane&15
        const float enk = enS[kk];
#define UPD(J, PJ1, PJ2, ZNJ) { \
        float dot  = acch[J] + accm[J] * (1.0f / ELS); \
        float dist = fmaf(-2.0f, dot, ZNJ + enk); \
        u64 p  = ((u64)__float_as_uint(dist) << 32) | (unsigned)kk; \
        u64 mx = p > PJ1 ? p : PJ1; \
        PJ1 = p < PJ1 ? p : PJ1; \
        PJ2 = mx < PJ2 ? mx : PJ2; }
        UPD(0, p1_0, p2_0, zn0) UPD(1, p1_1, p2_1, zn1)
        UPD(2, p1_2, p2_2, zn2) UPD(3, p1_3, p2_3, zn3)
#undef UPD
        if (ct < NTILE - 1) { cbh0 = nbh0; cbh1 = nbh1; cbl0 = nbl0; cbl1 = nbl1; }
    }

    // top-2 merge across the 16 lanes sharing each vector row
#pragma unroll
    for (int m = 1; m <= 8; m <<= 1) {
#define RED(PJ1, PJ2) { \
        u64 q1 = __shfl_xor(PJ1, m); u64 q2 = __shfl_xor(PJ2, m); \
        u64 lo = PJ1 < q1 ? PJ1 : q1; u64 hi = PJ1 < q1 ? q1 : PJ1; \
        u64 s2 = PJ2 < q2 ? PJ2 : q2; \
        PJ1 = lo; PJ2 = hi < s2 ? hi : s2; }
        RED(p1_0, p2_0) RED(p1_1, p2_1) RED(p1_2, p2_2) RED(p1_3, p2_3)
#undef RED
    }
    {
        const int j = lane & 15;
        if (j < 4) {
            u64 s1 = j == 0 ? p1_0 : j == 1 ? p1_1 : j == 2 ? p1_2 : p1_3;
            u64 s2 = j == 0 ? p2_0 : j == 1 ? p2_1 : j == 2 ? p2_2 : p2_3;
            const int v = vb + g4 * 4 + j;
            cand[v][0] = (int)(unsigned)s1;
            cand[v][1] = (int)(unsigned)s2;
        }
    }
    __syncthreads();

    // exact fp32 rescore of both candidates (ascending-d fmaf chain)
    if (tid < 128) {
        const int v = tid >> 1, c = tid & 1;
        const int k = cand[v][c];
        const float* xr = x + xbase + v * DIM;
        float dot = 0.f;
#pragma unroll
        for (int d = 0; d < DIM; ++d) dot = fmaf(xr[d], emb[d * KCODES + k], dot);
        exd[v][c] = fmaf(-2.0f, dot, znS[v] + enS[k]);
    }
    __syncthreads();
    if (tid < 64) {
        const int k0 = cand[tid][0], k1 = cand[tid][1];
        const float d0 = exd[tid][0], d1 = exd[tid][1];
        const bool take2 = (d1 < d0) || (d1 == d0 && k1 < k0);
        bksel[tid] = take2 ? k1 : k0;
    }
    __syncthreads();

    // epilogue: thread -> (vector v16, dim-block j16); coalesced stores
    const int v16 = tid >> 2;
    const int j16 = (tid & 3) * 16;
    const int bk  = bksel[v16];
    const int gvec = blockIdx.x * 64 + v16;
    const float* xg = x + (size_t)gvec * DIM + j16;
    float*       og = out + (size_t)gvec * DIM + j16;

    float lossLocal = 0.f;
#pragma unroll
    for (int c = 0; c < 4; ++c) {
        float4 q;
        q.x = emb[(j16 + c * 4 + 0) * KCODES + bk];
        q.y = emb[(j16 + c * 4 + 1) * KCODES + bk];
        q.z = emb[(j16 + c * 4 + 2) * KCODES + bk];
        q.w = emb[(j16 + c * 4 + 3) * KCODES + bk];
        *(float4*)(og + c * 4) = q;
        float4 xa = *(const float4*)(xg + c * 4);
        float a;
        a = q.x - xa.x; lossLocal = fmaf(a, a, lossLocal);
        a = q.y - xa.y; lossLocal = fmaf(a, a, lossLocal);
        a = q.z - xa.z; lossLocal = fmaf(a, a, lossLocal);
        a = q.w - xa.w; lossLocal = fmaf(a, a, lossLocal);
    }

    // block-reduce loss -> ONE partial store per block (no atomics)
#pragma unroll
    for (int off = 32; off; off >>= 1) lossLocal += __shfl_down(lossLocal, off, 64);
    if (lane == 0) swl[wid] = lossLocal;
    __syncthreads();
    if (tid == 0) part[WS_PART + blockIdx.x] = swl[0] + swl[1] + swl[2] + swl[3];
}

// Finish: reduce 1024 per-block partials, write the loss element.
__global__ __launch_bounds__(256, 1) void finish_kernel(const float* __restrict__ part,
                                                        float* __restrict__ out) {
    __shared__ float sw[4];
    const int tid = threadIdx.x, lane = tid & 63, wid = tid >> 6;
    float s = part[WS_PART + tid] + part[WS_PART + tid + 256]
            + part[WS_PART + tid + 512] + part[WS_PART + tid + 768];
#pragma unroll
    for (int off = 32; off; off >>= 1) s += __shfl_down(s, off, 64);
    if (lane == 0) sw[wid] = s;
    __syncthreads();
    if (tid == 0) {
        float total = sw[0] + sw[1] + sw[2] + sw[3];
        out[(size_t)NVEC * DIM] = 2.0f * total / (float)((size_t)NVEC * DIM);
    }
}

extern "C" void kernel_launch(void* const* d_in, const int* in_sizes, int n_in,
                              void* d_out, int out_size, void* d_ws, size_t ws_size,
                              hipStream_t stream) {
    const float* x   = (const float*)d_in[0];
    const float* emb = (const float*)d_in[1];
    float* out = (float*)d_out;
    float* ws  = (float*)d_ws;

    prep_kernel<<<dim3(9), dim3(512), 0, stream>>>(emb, ws);
    vq_kernel<<<dim3(NBLK), dim3(256), 0, stream>>>(x, emb, ws, out, ws);
    finish_kernel<<<dim3(1), dim3(256), 0, stream>>>(ws, out);
}

// Round 9
// 45.733 us; speedup vs baseline: 77.9399x; 1.2543x over previous
//
#include <hip/hip_runtime.h>

// B*H*W = 65536 vectors, dim 64, 512 codes
#define NVEC 65536
#define DIM 64
#define KCODES 512
#define VPB 128       // vectors per block
#define NBLK 512      // NVEC / VPB
#define NTILE 32      // 512 codes / 16 per MFMA col-tile
#define ELS 2048.0f   // residual pre-scale (avoids fp16 denormals)
#define GAP_THR 2e-4f // rescore guard: >> max split-fp16 ordering error (~1e-5)

typedef _Float16 f16x8 __attribute__((ext_vector_type(8)));
typedef float    f32x4 __attribute__((ext_vector_type(4)));
typedef unsigned long long u64;

// ws layout (floats):
#define WS_EN   4                   // [4..516) codebook norms
#define WS_EH   1024                // [1024..17408) hi fp16 B-fragments
#define WS_EL   (1024 + 16384)      // [17408..33792) residual fp16 B-fragments
#define WS_PART 33792               // [33792..34304) per-block loss partials
#define WS_EMBT 34816               // [34816..67584) embT[k][d] transposed codebook

// Prep (17 blocks x 512):
//  b=0     : exact codebook norms (reference fmaf chain)
//  b=1..8  : pack E into per-lane MFMA B-fragments (hi + scaled residual)
//  b=9..16 : transpose emb -> embT[k][d] via LDS tile (coalesced both sides)
__global__ __launch_bounds__(512, 1) void prep_kernel(const float* __restrict__ emb,
                                                      float* __restrict__ ws) {
    const int tid = threadIdx.x;
    const int b   = blockIdx.x;
    if (b == 0) {
        float s = 0.f;
#pragma unroll
        for (int d = 0; d < DIM; ++d) { float v = emb[d * KCODES + tid]; s = fmaf(v, v, s); }
        ws[WS_EN + tid] = s;
    } else if (b <= 8) {
        const int fl = (b - 1) * 512 + tid;            // fragment-lane id, 0..4095
        const int ct = fl >> 7, s5 = (fl >> 6) & 1, l = fl & 63;
        const int k  = ct * 16 + (l & 15);             // B col
        const int d0 = s5 * 32 + (l >> 4) * 8;         // B k-rows (d)
        f16x8 eh, el;
#pragma unroll
        for (int e = 0; e < 8; ++e) {
            float v = emb[(d0 + e) * KCODES + k];
            _Float16 h = (_Float16)v;
            eh[e] = h;
            el[e] = (_Float16)((v - (float)h) * ELS);
        }
        ((f16x8*)(ws + WS_EH))[fl] = eh;
        ((f16x8*)(ws + WS_EL))[fl] = el;
    } else {
        __shared__ float tl[64][65];
        const int kt = b - 9;          // k-tile 0..7
        const int r  = tid >> 3;       // 0..63
        const int g  = tid & 7;
#pragma unroll
        for (int i = 0; i < 8; ++i)
            tl[r][g * 8 + i] = emb[r * KCODES + kt * 64 + g * 8 + i];
        __syncthreads();
#pragma unroll
        for (int i = 0; i < 8; ++i)
            ws[WS_EMBT + (kt * 64 + r) * 64 + g * 8 + i] = tl[g * 8 + i][r];
    }
}

// Main: 512 thr = 8 waves, 128 vectors/block, grid 512 = 2 blocks/CU -> ALL
// blocks co-resident (one round, 16 waves/CU). Each wave owns 16 vectors and
// scans 512 codes in 32 col-tiles of 6 mfma_f32_16x16x32_f16 (split-fp16:
// zh*eh + (zl_s*eh + zh*el_s)/ELS). Packed-u64 top-2 + 16-lane shfl reduce.
// Exact fp32 rescore ONLY when approx top-2 gap <= GAP_THR (rare); epilogue
// gathers q from embT (coalesced float4 rows). No atomics anywhere.
__global__ __launch_bounds__(512, 2) void vq_kernel(const float* __restrict__ x,
                                                    const float* __restrict__ emb,
                                                    const float* __restrict__ ws_ro,
                                                    float* __restrict__ out,
                                                    float* __restrict__ part) {
    __shared__ f16x8 zhS[VPB][8];   // [v][u], u = (d>>3) ^ (v&7)  (bank swizzle)
    __shared__ f16x8 zlS[VPB][8];
    __shared__ float enS[KCODES];
    __shared__ float znS[VPB];
    __shared__ int   cand[VPB][2];
    __shared__ float sdf[VPB][2];
    __shared__ float exd[VPB][2];
    __shared__ int   bksel[VPB];
    __shared__ float swl[8];

    const int tid  = threadIdx.x;
    const int wid  = tid >> 6;            // 0..7
    const int lane = tid & 63;
    const size_t xbase = (size_t)blockIdx.x * VPB * DIM;

    enS[tid] = ws_ro[WS_EN + tid];        // 512 threads, one code each

    // x-block -> fp16 hi + scaled residual (swizzled LDS); znorm via shfl
    {
        const int v  = tid >> 2;          // 0..127
        const int d0 = (tid & 3) * 16;
        const float* xp = x + xbase + v * DIM + d0;
        float4 a = *(const float4*)(xp);
        float4 b = *(const float4*)(xp + 4);
        float4 c = *(const float4*)(xp + 8);
        float4 e = *(const float4*)(xp + 12);
        float t0[8] = {a.x, a.y, a.z, a.w, b.x, b.y, b.z, b.w};
        float t1[8] = {c.x, c.y, c.z, c.w, e.x, e.y, e.z, e.w};
        float pz = 0.f;
#pragma unroll
        for (int i = 0; i < 8; ++i) pz = fmaf(t0[i], t0[i], pz);
#pragma unroll
        for (int i = 0; i < 8; ++i) pz = fmaf(t1[i], t1[i], pz);
        pz += __shfl_xor(pz, 1);
        pz += __shfl_xor(pz, 2);          // 4-thread group shares one vector
        if ((tid & 3) == 0) znS[v] = pz;
        f16x8 h0, l0, h1, l1;
#pragma unroll
        for (int i = 0; i < 8; ++i) {
            _Float16 h = (_Float16)t0[i]; h0[i] = h; l0[i] = (_Float16)((t0[i] - (float)h) * ELS);
            _Float16 g = (_Float16)t1[i]; h1[i] = g; l1[i] = (_Float16)((t1[i] - (float)g) * ELS);
        }
        const int u0 = ((d0 >> 3))     ^ (v & 7);
        const int u1 = ((d0 >> 3) + 1) ^ (v & 7);
        zhS[v][u0] = h0; zhS[v][u1] = h1;
        zlS[v][u0] = l0; zlS[v][u1] = l1;
    }
    __syncthreads();

    // A-fragments: row = lane&15 (vector), k = (lane>>4)*8 + e  (+32 for s=1)
    const int vb = wid * 16;
    const int vA = vb + (lane & 15);
    const int g4 = lane >> 4;
    const int sw = vA & 7;
    f16x8 ah0 = zhS[vA][(g4)     ^ sw];
    f16x8 ah1 = zhS[vA][(4 + g4) ^ sw];
    f16x8 al0 = zlS[vA][(g4)     ^ sw];
    f16x8 al1 = zlS[vA][(4 + g4) ^ sw];
    const float zn0 = znS[vb + g4 * 4 + 0];
    const float zn1 = znS[vb + g4 * 4 + 1];
    const float zn2 = znS[vb + g4 * 4 + 2];
    const float zn3 = znS[vb + g4 * 4 + 3];

    const f16x8* ehp = (const f16x8*)(ws_ro + WS_EH);
    const f16x8* elp = (const f16x8*)(ws_ro + WS_EL);

    u64 p1_0 = ~0ull, p1_1 = ~0ull, p1_2 = ~0ull, p1_3 = ~0ull;
    u64 p2_0 = ~0ull, p2_1 = ~0ull, p2_2 = ~0ull, p2_3 = ~0ull;

    // register double-buffer of B-fragments
    f16x8 cbh0 = ehp[lane], cbh1 = ehp[64 + lane];
    f16x8 cbl0 = elp[lane], cbl1 = elp[64 + lane];

#pragma unroll 1
    for (int ct = 0; ct < NTILE; ++ct) {
        f16x8 nbh0, nbh1, nbl0, nbl1;
        if (ct < NTILE - 1) {
            nbh0 = ehp[(ct * 2 + 2) * 64 + lane];
            nbh1 = ehp[(ct * 2 + 3) * 64 + lane];
            nbl0 = elp[(ct * 2 + 2) * 64 + lane];
            nbl1 = elp[(ct * 2 + 3) * 64 + lane];
        }
        f32x4 acch = {0.f, 0.f, 0.f, 0.f};
        f32x4 accm = {0.f, 0.f, 0.f, 0.f};
        acch = __builtin_amdgcn_mfma_f32_16x16x32_f16(ah0, cbh0, acch, 0, 0, 0);
        acch = __builtin_amdgcn_mfma_f32_16x16x32_f16(ah1, cbh1, acch, 0, 0, 0);
        accm = __builtin_amdgcn_mfma_f32_16x16x32_f16(al0, cbh0, accm, 0, 0, 0);
        accm = __builtin_amdgcn_mfma_f32_16x16x32_f16(al1, cbh1, accm, 0, 0, 0);
        accm = __builtin_amdgcn_mfma_f32_16x16x32_f16(ah0, cbl0, accm, 0, 0, 0);
        accm = __builtin_amdgcn_mfma_f32_16x16x32_f16(ah1, cbl1, accm, 0, 0, 0);
        const int   kk  = ct * 16 + (lane & 15);   // C/D col = lane&15
        const float enk = enS[kk];
#define UPD(J, PJ1, PJ2, ZNJ) { \
        float dot  = acch[J] + accm[J] * (1.0f / ELS); \
        float dist = fmaf(-2.0f, dot, ZNJ + enk); \
        u64 p  = ((u64)__float_as_uint(dist) << 32) | (unsigned)kk; \
        u64 mx = p > PJ1 ? p : PJ1; \
        PJ1 = p < PJ1 ? p : PJ1; \
        PJ2 = mx < PJ2 ? mx : PJ2; }
        UPD(0, p1_0, p2_0, zn0) UPD(1, p1_1, p2_1, zn1)
        UPD(2, p1_2, p2_2, zn2) UPD(3, p1_3, p2_3, zn3)
#undef UPD
        if (ct < NTILE - 1) { cbh0 = nbh0; cbh1 = nbh1; cbl0 = nbl0; cbl1 = nbl1; }
    }

    // top-2 merge across the 16 lanes sharing each vector row
#pragma unroll
    for (int m = 1; m <= 8; m <<= 1) {
#define RED(PJ1, PJ2) { \
        u64 q1 = __shfl_xor(PJ1, m); u64 q2 = __shfl_xor(PJ2, m); \
        u64 lo = PJ1 < q1 ? PJ1 : q1; u64 hi = PJ1 < q1 ? q1 : PJ1; \
        u64 s2 = PJ2 < q2 ? PJ2 : q2; \
        PJ1 = lo; PJ2 = hi < s2 ? hi : s2; }
        RED(p1_0, p2_0) RED(p1_1, p2_1) RED(p1_2, p2_2) RED(p1_3, p2_3)
#undef RED
    }
    {
        const int j = lane & 15;
        if (j < 4) {
            u64 s1 = j == 0 ? p1_0 : j == 1 ? p1_1 : j == 2 ? p1_2 : p1_3;
            u64 s2 = j == 0 ? p2_0 : j == 1 ? p2_1 : j == 2 ? p2_2 : p2_3;
            const int v = vb + g4 * 4 + j;
            cand[v][0] = (int)(unsigned)s1;
            cand[v][1] = (int)(unsigned)s2;
            sdf[v][0]  = __uint_as_float((unsigned)(s1 >> 32));
            sdf[v][1]  = __uint_as_float((unsigned)(s2 >> 32));
        }
    }
    __syncthreads();

    // conditional exact rescore: only when approx gap could flip the argmin.
    // Rare path is fully reference-exact (ascending-d zn chain + dot chain).
    if (tid < 256) {
        const int v = tid >> 1, c = tid & 1;
        const float dA = sdf[v][0], dB = sdf[v][1];
        float res = sdf[v][c];
        if (dB - dA <= GAP_THR) {
            const int k = cand[v][c];
            const float* xr = x + xbase + v * DIM;
            const float* er = ws_ro + WS_EMBT + k * 64;   // embT row (coalesced-ish)
            float zn = 0.f, dot = 0.f;
#pragma unroll
            for (int d = 0; d < DIM; ++d) {
                float xv = xr[d];
                zn  = fmaf(xv, xv, zn);
                dot = fmaf(xv, er[d], dot);
            }
            res = fmaf(-2.0f, dot, zn + enS[k]);
        }
        exd[v][c] = res;
    }
    __syncthreads();
    if (tid < VPB) {
        const int k0 = cand[tid][0], k1 = cand[tid][1];
        const float d0 = exd[tid][0], d1 = exd[tid][1];
        const bool take2 = (d1 < d0) || (d1 == d0 && k1 < k0);
        bksel[tid] = take2 ? k1 : k0;
    }
    __syncthreads();

    // epilogue: thread -> (vector v16, dim-block j16); q from embT rows
    const int v16 = tid >> 2;             // 0..127
    const int j16 = (tid & 3) * 16;
    const int bk  = bksel[v16];
    const int gvec = blockIdx.x * VPB + v16;
    const float*  xg  = x + (size_t)gvec * DIM + j16;
    float*        og  = out + (size_t)gvec * DIM + j16;
    const float4* et4 = (const float4*)(ws_ro + WS_EMBT + bk * 64);

    float lossLocal = 0.f;
#pragma unroll
    for (int c = 0; c < 4; ++c) {
        float4 q  = et4[(tid & 3) * 4 + c];          // coalesced 256B per 4-thread group
        *(float4*)(og + c * 4) = q;
        float4 xa = *(const float4*)(xg + c * 4);
        float a;
        a = q.x - xa.x; lossLocal = fmaf(a, a, lossLocal);
        a = q.y - xa.y; lossLocal = fmaf(a, a, lossLocal);
        a = q.z - xa.z; lossLocal = fmaf(a, a, lossLocal);
        a = q.w - xa.w; lossLocal = fmaf(a, a, lossLocal);
    }

    // block-reduce loss -> ONE partial store per block (no atomics)
#pragma unroll
    for (int off = 32; off; off >>= 1) lossLocal += __shfl_down(lossLocal, off, 64);
    if (lane == 0) swl[wid] = lossLocal;
    __syncthreads();
    if (tid == 0) {
        float s = 0.f;
#pragma unroll
        for (int i = 0; i < 8; ++i) s += swl[i];
        part[WS_PART + blockIdx.x] = s;
    }
}

// Finish: reduce 512 per-block partials, write the loss element.
__global__ __launch_bounds__(256, 1) void finish_kernel(const float* __restrict__ part,
                                                        float* __restrict__ out) {
    __shared__ float sw[4];
    const int tid = threadIdx.x, lane = tid & 63, wid = tid >> 6;
    float s = part[WS_PART + tid] + part[WS_PART + tid + 256];
#pragma unroll
    for (int off = 32; off; off >>= 1) s += __shfl_down(s, off, 64);
    if (lane == 0) sw[wid] = s;
    __syncthreads();
    if (tid == 0) {
        float total = sw[0] + sw[1] + sw[2] + sw[3];
        out[(size_t)NVEC * DIM] = 2.0f * total / (float)((size_t)NVEC * DIM);
    }
}

extern "C" void kernel_launch(void* const* d_in, const int* in_sizes, int n_in,
                              void* d_out, int out_size, void* d_ws, size_t ws_size,
                              hipStream_t stream) {
    const float* x   = (const float*)d_in[0];
    const float* emb = (const float*)d_in[1];
    float* out = (float*)d_out;
    float* ws  = (float*)d_ws;

    prep_kernel<<<dim3(17), dim3(512), 0, stream>>>(emb, ws);
    vq_kernel<<<dim3(NBLK), dim3(512), 0, stream>>>(x, emb, ws, out, ws);
    finish_kernel<<<dim3(1), dim3(256), 0, stream>>>(ws, out);
}